// Round 1
// baseline (1343.185 us; speedup 1.0000x reference)
//
#include <hip/hip_runtime.h>

#define N_NODES_C 100000
#define N_EDGES_C 1200000

__device__ __forceinline__ void atomic_add_f32(float* p, float v) {
    __hip_atomic_fetch_add(p, v, __ATOMIC_RELAXED, __HIP_MEMORY_SCOPE_AGENT);
}

__global__ void deg_init_kernel(int* __restrict__ deg, int n) {
    int i = blockIdx.x * blockDim.x + threadIdx.x;
    if (i < n) deg[i] = 1;  // self-loop
}

__global__ void deg_count_kernel(const int* __restrict__ dst, int* __restrict__ deg, int e) {
    int i = blockIdx.x * blockDim.x + threadIdx.x;
    if (i < e) atomicAdd(&deg[dst[i]], 1);
}

__global__ void dinv_kernel(const int* __restrict__ deg, float* __restrict__ dinv, int n) {
    int i = blockIdx.x * blockDim.x + threadIdx.x;
    if (i < n) dinv[i] = rsqrtf((float)deg[i]);
}

// out[node][c] = (sum_k in[node][k] * W[k][c]) * dinv[node]   (W is 64x64 row-major)
__global__ void matmul64_scale_kernel(const float* __restrict__ in, const float* __restrict__ W,
                                      const float* __restrict__ dinv, float* __restrict__ out, int n) {
    __shared__ __align__(16) float wlds[64 * 64];
    __shared__ __align__(16) float xlds[4][64];
    int tid = threadIdx.x;
    #pragma unroll
    for (int i = 0; i < 16; ++i) wlds[tid + i * 256] = W[tid + i * 256];
    int r = tid >> 6, c = tid & 63;
    int node = blockIdx.x * 4 + r;
    if (node < n) xlds[r][c] = in[node * 64 + c];
    __syncthreads();
    if (node >= n) return;
    float acc = 0.f;
    #pragma unroll
    for (int k = 0; k < 64; ++k) acc = fmaf(xlds[r][k], wlds[k * 64 + c], acc);
    out[node * 64 + c] = acc * dinv[node];
}

// one wave per edge: acc[dst][lane] += ts[src][lane]
__global__ void aggregate_kernel(const int* __restrict__ src, const int* __restrict__ dst,
                                 const float* __restrict__ ts, float* __restrict__ acc, int e) {
    int w = (blockIdx.x * blockDim.x + threadIdx.x) >> 6;
    int lane = threadIdx.x & 63;
    if (w >= e) return;
    int s = src[w];
    int d = dst[w];
    float v = ts[s * 64 + lane];
    atomic_add_f32(&acc[d * 64 + lane], v);
}

// out[i][c] = [relu]( dinv[i]*acc[i][c] + b[c] )
__global__ void finalize_kernel(const float* __restrict__ acc, const float* __restrict__ dinv,
                                const float* __restrict__ b, float* __restrict__ out, int n, int do_relu) {
    int idx = blockIdx.x * blockDim.x + threadIdx.x;
    if (idx >= n * 64) return;
    int i = idx >> 6, c = idx & 63;
    float v = dinv[i] * acc[idx] + b[c];
    if (do_relu) v = fmaxf(v, 0.f);
    out[idx] = v;
}

__global__ void out_init_kernel(const float* __restrict__ bp2, float* __restrict__ out, int n) {
    int idx = blockIdx.x * blockDim.x + threadIdx.x;
    if (idx < n * 3) out[idx] = bp2[idx % 3];
}

// Fused MLP head: in = [gnn(64) | x(64)]; h2 = relu(in @ Wp1 + bp1) [512]; out3 = h2 @ Wp2 (+bp2 via init)
// Each block: 256 nodes (thread-per-node), covers half the 512 columns (2 x 128-col LDS quarters).
__launch_bounds__(256, 2)
__global__ void mlp_kernel(const float* __restrict__ gnn, const float* __restrict__ x,
                           const float* __restrict__ Wp1, const float* __restrict__ bp1,
                           const float* __restrict__ Wp2, float* __restrict__ out, int n) {
    __shared__ __align__(16) float wlds[128 * 128];   // 64 KB quarter of Wp1, layout [k][cq]
    __shared__ __align__(16) float w2lds[128 * 3];
    __shared__ __align__(16) float b1lds[128];
    int tid = threadIdx.x;
    int half = blockIdx.x & 1;
    int node = (blockIdx.x >> 1) * 256 + tid;
    bool active = node < n;

    float in[128];
    if (active) {
        const float4* g4 = (const float4*)(gnn + (size_t)node * 64);
        const float4* x4 = (const float4*)(x + (size_t)node * 64);
        #pragma unroll
        for (int i = 0; i < 16; ++i) {
            float4 v = g4[i];
            in[i * 4 + 0] = v.x; in[i * 4 + 1] = v.y; in[i * 4 + 2] = v.z; in[i * 4 + 3] = v.w;
        }
        #pragma unroll
        for (int i = 0; i < 16; ++i) {
            float4 v = x4[i];
            in[64 + i * 4 + 0] = v.x; in[64 + i * 4 + 1] = v.y; in[64 + i * 4 + 2] = v.z; in[64 + i * 4 + 3] = v.w;
        }
    }

    float acc0 = 0.f, acc1 = 0.f, acc2 = 0.f;
    for (int qi = 0; qi < 2; ++qi) {
        int q = half * 2 + qi;
        __syncthreads();
        // stage quarter of Wp1: wlds[k*128+cq] = Wp1[k*512 + q*128 + cq]
        for (int i = 0; i < 64; ++i) {
            int idx = tid + i * 256;
            int k = idx >> 7, cq = idx & 127;
            wlds[idx] = Wp1[k * 512 + q * 128 + cq];
        }
        if (tid < 128) b1lds[tid] = bp1[q * 128 + tid];
        for (int i = tid; i < 384; i += 256) w2lds[i] = Wp2[q * 384 + i];
        __syncthreads();
        if (active) {
            for (int cq = 0; cq < 128; cq += 4) {
                float s0 = b1lds[cq + 0], s1 = b1lds[cq + 1], s2 = b1lds[cq + 2], s3 = b1lds[cq + 3];
                #pragma unroll
                for (int k = 0; k < 128; ++k) {
                    float4 w = *(const float4*)&wlds[k * 128 + cq];
                    float xv = in[k];
                    s0 = fmaf(xv, w.x, s0);
                    s1 = fmaf(xv, w.y, s1);
                    s2 = fmaf(xv, w.z, s2);
                    s3 = fmaf(xv, w.w, s3);
                }
                s0 = fmaxf(s0, 0.f); s1 = fmaxf(s1, 0.f); s2 = fmaxf(s2, 0.f); s3 = fmaxf(s3, 0.f);
                acc0 = fmaf(s0, w2lds[(cq + 0) * 3 + 0], acc0);
                acc1 = fmaf(s0, w2lds[(cq + 0) * 3 + 1], acc1);
                acc2 = fmaf(s0, w2lds[(cq + 0) * 3 + 2], acc2);
                acc0 = fmaf(s1, w2lds[(cq + 1) * 3 + 0], acc0);
                acc1 = fmaf(s1, w2lds[(cq + 1) * 3 + 1], acc1);
                acc2 = fmaf(s1, w2lds[(cq + 1) * 3 + 2], acc2);
                acc0 = fmaf(s2, w2lds[(cq + 2) * 3 + 0], acc0);
                acc1 = fmaf(s2, w2lds[(cq + 2) * 3 + 1], acc1);
                acc2 = fmaf(s2, w2lds[(cq + 2) * 3 + 2], acc2);
                acc0 = fmaf(s3, w2lds[(cq + 3) * 3 + 0], acc0);
                acc1 = fmaf(s3, w2lds[(cq + 3) * 3 + 1], acc1);
                acc2 = fmaf(s3, w2lds[(cq + 3) * 3 + 2], acc2);
            }
        }
    }
    if (active) {
        atomic_add_f32(&out[node * 3 + 0], acc0);
        atomic_add_f32(&out[node * 3 + 1], acc1);
        atomic_add_f32(&out[node * 3 + 2], acc2);
    }
}

extern "C" void kernel_launch(void* const* d_in, const int* in_sizes, int n_in,
                              void* d_out, int out_size, void* d_ws, size_t ws_size,
                              hipStream_t stream) {
    const float* x   = (const float*)d_in[0];
    const int*   ei  = (const int*)d_in[1];   // [2][E]
    const float* W1  = (const float*)d_in[2];
    const float* b1  = (const float*)d_in[3];
    const float* W2  = (const float*)d_in[4];
    const float* b2  = (const float*)d_in[5];
    const float* Wp1 = (const float*)d_in[6];
    const float* bp1 = (const float*)d_in[7];
    const float* Wp2 = (const float*)d_in[8];
    const float* bp2 = (const float*)d_in[9];
    float* out = (float*)d_out;

    const int n = N_NODES_C;
    const int e = N_EDGES_C;
    const int* src = ei;
    const int* dst = ei + e;

    char* ws = (char*)d_ws;
    size_t o = 0;
    int* deg = (int*)(ws + o);          o += ((size_t)n * 4 + 511) & ~(size_t)511;
    float* dinv = (float*)(ws + o);     o += ((size_t)n * 4 + 511) & ~(size_t)511;
    float* bufA = (float*)(ws + o);     o += ((size_t)n * 64 * 4 + 511) & ~(size_t)511;
    float* bufB = (float*)(ws + o);     o += ((size_t)n * 64 * 4 + 511) & ~(size_t)511;

    const size_t rowbytes = (size_t)n * 64 * 4;

    // degrees & dinv
    hipLaunchKernelGGL(deg_init_kernel, dim3((n + 255) / 256), dim3(256), 0, stream, deg, n);
    hipLaunchKernelGGL(deg_count_kernel, dim3((e + 255) / 256), dim3(256), 0, stream, dst, deg, e);
    hipLaunchKernelGGL(dinv_kernel, dim3((n + 255) / 256), dim3(256), 0, stream, deg, dinv, n);

    // ----- GCN layer 1: h1 = relu(conv(x, W1, b1)) -----
    hipLaunchKernelGGL(matmul64_scale_kernel, dim3((n + 3) / 4), dim3(256), 0, stream, x, W1, dinv, bufA, n);
    hipMemcpyAsync(bufB, bufA, rowbytes, hipMemcpyDeviceToDevice, stream);    // acc init = self-loop term
    hipLaunchKernelGGL(aggregate_kernel, dim3(((size_t)e * 64 + 255) / 256), dim3(256), 0, stream, src, dst, bufA, bufB, e);
    hipLaunchKernelGGL(finalize_kernel, dim3((n * 64 + 255) / 256), dim3(256), 0, stream, bufB, dinv, b1, bufA, n, 1);
    // h1 in bufA

    // ----- GCN layer 2: gnn = conv(h1, W2, b2) -----
    hipLaunchKernelGGL(matmul64_scale_kernel, dim3((n + 3) / 4), dim3(256), 0, stream, bufA, W2, dinv, bufB, n);
    hipMemcpyAsync(bufA, bufB, rowbytes, hipMemcpyDeviceToDevice, stream);
    hipLaunchKernelGGL(aggregate_kernel, dim3(((size_t)e * 64 + 255) / 256), dim3(256), 0, stream, src, dst, bufB, bufA, e);
    hipLaunchKernelGGL(finalize_kernel, dim3((n * 64 + 255) / 256), dim3(256), 0, stream, bufA, dinv, b2, bufB, n, 0);
    // gnn_out in bufB

    // ----- MLP head -----
    hipLaunchKernelGGL(out_init_kernel, dim3((n * 3 + 255) / 256), dim3(256), 0, stream, bp2, out, n);
    int chunks = (n + 255) / 256;
    hipLaunchKernelGGL(mlp_kernel, dim3(chunks * 2), dim3(256), 0, stream, bufB, x, Wp1, bp1, Wp2, out, n);
}

// Round 2
// 954.583 us; speedup vs baseline: 1.4071x; 1.4071x over previous
//
#include <hip/hip_runtime.h>

#define N_NODES_C 100000
#define N_EDGES_C 1200000

__device__ __forceinline__ void atomic_add_f32(float* p, float v) {
    __hip_atomic_fetch_add(p, v, __ATOMIC_RELAXED, __HIP_MEMORY_SCOPE_AGENT);
}

__global__ void deg_init_kernel(int* __restrict__ deg, int n) {
    int i = blockIdx.x * blockDim.x + threadIdx.x;
    if (i < n) deg[i] = 1;  // self-loop
}

__global__ void deg_count_kernel(const int* __restrict__ dst, int* __restrict__ deg, int e) {
    int i = blockIdx.x * blockDim.x + threadIdx.x;
    if (i < e) atomicAdd(&deg[dst[i]], 1);
}

__global__ void dinv_kernel(const int* __restrict__ deg, float* __restrict__ dinv, int n) {
    int i = blockIdx.x * blockDim.x + threadIdx.x;
    if (i < n) dinv[i] = rsqrtf((float)deg[i]);
}

// out[node][c] = (sum_k in[node][k] * W[k][c]) * dinv[node]   (W is 64x64 row-major)
__global__ void matmul64_scale_kernel(const float* __restrict__ in, const float* __restrict__ W,
                                      const float* __restrict__ dinv, float* __restrict__ out, int n) {
    __shared__ __align__(16) float wlds[64 * 64];
    __shared__ __align__(16) float xlds[4][64];
    int tid = threadIdx.x;
    #pragma unroll
    for (int i = 0; i < 16; ++i) wlds[tid + i * 256] = W[tid + i * 256];
    int r = tid >> 6, c = tid & 63;
    int node = blockIdx.x * 4 + r;
    if (node < n) xlds[r][c] = in[node * 64 + c];
    __syncthreads();
    if (node >= n) return;
    float acc = 0.f;
    #pragma unroll
    for (int k = 0; k < 64; ++k) acc = fmaf(xlds[r][k], wlds[k * 64 + c], acc);
    out[node * 64 + c] = acc * dinv[node];
}

// one wave per edge: acc[dst][lane] += ts[src][lane]
__global__ void aggregate_kernel(const int* __restrict__ src, const int* __restrict__ dst,
                                 const float* __restrict__ ts, float* __restrict__ acc, int e) {
    int w = (blockIdx.x * blockDim.x + threadIdx.x) >> 6;
    int lane = threadIdx.x & 63;
    if (w >= e) return;
    int s = src[w];
    int d = dst[w];
    float v = ts[s * 64 + lane];
    atomic_add_f32(&acc[d * 64 + lane], v);
}

// out[i][c] = [relu]( dinv[i]*acc[i][c] + b[c] )
__global__ void finalize_kernel(const float* __restrict__ acc, const float* __restrict__ dinv,
                                const float* __restrict__ b, float* __restrict__ out, int n, int do_relu) {
    int idx = blockIdx.x * blockDim.x + threadIdx.x;
    if (idx >= n * 64) return;
    int i = idx >> 6, c = idx & 63;
    float v = dinv[i] * acc[idx] + b[c];
    if (do_relu) v = fmaxf(v, 0.f);
    out[idx] = v;
}

__global__ void out_init_kernel(const float* __restrict__ bp2, float* __restrict__ out, int n) {
    int idx = blockIdx.x * blockDim.x + threadIdx.x;
    if (idx < n * 3) out[idx] = bp2[idx % 3];
}

// Fused MLP head as register-tiled GEMM.
// in = [gnn(64) | x(64)] (K=128); h2 = relu(in @ Wp1 + bp1) [512]; out3 += h2 @ Wp2.
// Block: 64 nodes x 64 cols, 256 threads (16 tx-colgroups x 16 ty-nodegroups), 4x4 per thread.
// Grid: (ceil(n/64)) x 8 col-blocks; cb = blockIdx.x & 7.
__launch_bounds__(256, 2)
__global__ void mlp_gemm_kernel(const float* __restrict__ gnn, const float* __restrict__ x,
                                const float* __restrict__ Wp1, const float* __restrict__ bp1,
                                const float* __restrict__ Wp2, float* __restrict__ out, int n) {
    __shared__ __align__(16) float a_lds[128 * 64];   // [k][node], 32 KB
    __shared__ __align__(16) float w_lds[128 * 64];   // [k][cq],   32 KB
    __shared__ __align__(16) float w2lds[64 * 3];
    __shared__ float b1lds[64];

    int tid = threadIdx.x;
    int cb = blockIdx.x & 7;
    int nb = blockIdx.x >> 3;
    int node0 = nb * 64;

    // stage A (transposed): a_lds[k*64+node] = concat(gnn,x)[node0+node][k]
    {
        int node = tid & 63;
        int gnode = node0 + node;
        bool ok = gnode < n;
        const float4* g4 = (const float4*)(gnn + (size_t)gnode * 64);
        const float4* x4 = (const float4*)(x + (size_t)gnode * 64);
        #pragma unroll
        for (int i = 0; i < 8; ++i) {
            int k4 = (tid >> 6) + i * 4;   // 0..31
            float4 v = make_float4(0.f, 0.f, 0.f, 0.f);
            if (ok) v = (k4 < 16) ? g4[k4] : x4[k4 - 16];
            int k = k4 * 4;
            a_lds[(k + 0) * 64 + node] = v.x;   // banks: node%32 -> 2-way, free
            a_lds[(k + 1) * 64 + node] = v.y;
            a_lds[(k + 2) * 64 + node] = v.z;
            a_lds[(k + 3) * 64 + node] = v.w;
        }
    }
    // stage W1 tile: w_lds[k*64+cq] = Wp1[k*512 + cb*64 + cq] (coalesced read)
    #pragma unroll
    for (int i = 0; i < 32; ++i) {
        int idx = tid + i * 256;
        int k = idx >> 6, cq = idx & 63;
        w_lds[idx] = Wp1[k * 512 + cb * 64 + cq];
    }
    if (tid < 64) b1lds[tid] = bp1[cb * 64 + tid];
    if (tid < 192) w2lds[tid] = Wp2[cb * 192 + tid];
    __syncthreads();

    int tx = tid & 15, ty = (tid >> 4) & 15;
    float acc[4][4];
    #pragma unroll
    for (int m = 0; m < 4; ++m)
        #pragma unroll
        for (int c = 0; c < 4; ++c) acc[m][c] = 0.f;

    const float* ap = a_lds + ty * 4;
    const float* bp = w_lds + tx * 4;
    #pragma unroll 8
    for (int k = 0; k < 128; ++k) {
        float4 a = *(const float4*)(ap + k * 64);
        float4 b = *(const float4*)(bp + k * 64);
        acc[0][0] = fmaf(a.x, b.x, acc[0][0]);
        acc[0][1] = fmaf(a.x, b.y, acc[0][1]);
        acc[0][2] = fmaf(a.x, b.z, acc[0][2]);
        acc[0][3] = fmaf(a.x, b.w, acc[0][3]);
        acc[1][0] = fmaf(a.y, b.x, acc[1][0]);
        acc[1][1] = fmaf(a.y, b.y, acc[1][1]);
        acc[1][2] = fmaf(a.y, b.z, acc[1][2]);
        acc[1][3] = fmaf(a.y, b.w, acc[1][3]);
        acc[2][0] = fmaf(a.z, b.x, acc[2][0]);
        acc[2][1] = fmaf(a.z, b.y, acc[2][1]);
        acc[2][2] = fmaf(a.z, b.z, acc[2][2]);
        acc[2][3] = fmaf(a.z, b.w, acc[2][3]);
        acc[3][0] = fmaf(a.w, b.x, acc[3][0]);
        acc[3][1] = fmaf(a.w, b.y, acc[3][1]);
        acc[3][2] = fmaf(a.w, b.z, acc[3][2]);
        acc[3][3] = fmaf(a.w, b.w, acc[3][3]);
    }

    // epilogue: bias + relu + @Wp2(64x3) partial, reduce over tx, atomic into out
    float pr[4][3];
    #pragma unroll
    for (int m = 0; m < 4; ++m) {
        pr[m][0] = 0.f; pr[m][1] = 0.f; pr[m][2] = 0.f;
        #pragma unroll
        for (int c = 0; c < 4; ++c) {
            float h = fmaxf(acc[m][c] + b1lds[tx * 4 + c], 0.f);
            pr[m][0] = fmaf(h, w2lds[(tx * 4 + c) * 3 + 0], pr[m][0]);
            pr[m][1] = fmaf(h, w2lds[(tx * 4 + c) * 3 + 1], pr[m][1]);
            pr[m][2] = fmaf(h, w2lds[(tx * 4 + c) * 3 + 2], pr[m][2]);
        }
    }
    #pragma unroll
    for (int m = 0; m < 4; ++m)
        #pragma unroll
        for (int j = 0; j < 3; ++j) {
            float v = pr[m][j];
            v += __shfl_xor(v, 1);
            v += __shfl_xor(v, 2);
            v += __shfl_xor(v, 4);
            v += __shfl_xor(v, 8);
            pr[m][j] = v;
        }
    if (tx == 0) {
        #pragma unroll
        for (int m = 0; m < 4; ++m) {
            int node = node0 + ty * 4 + m;
            if (node < n) {
                atomic_add_f32(&out[node * 3 + 0], pr[m][0]);
                atomic_add_f32(&out[node * 3 + 1], pr[m][1]);
                atomic_add_f32(&out[node * 3 + 2], pr[m][2]);
            }
        }
    }
}

extern "C" void kernel_launch(void* const* d_in, const int* in_sizes, int n_in,
                              void* d_out, int out_size, void* d_ws, size_t ws_size,
                              hipStream_t stream) {
    const float* x   = (const float*)d_in[0];
    const int*   ei  = (const int*)d_in[1];   // [2][E]
    const float* W1  = (const float*)d_in[2];
    const float* b1  = (const float*)d_in[3];
    const float* W2  = (const float*)d_in[4];
    const float* b2  = (const float*)d_in[5];
    const float* Wp1 = (const float*)d_in[6];
    const float* bp1 = (const float*)d_in[7];
    const float* Wp2 = (const float*)d_in[8];
    const float* bp2 = (const float*)d_in[9];
    float* out = (float*)d_out;

    const int n = N_NODES_C;
    const int e = N_EDGES_C;
    const int* src = ei;
    const int* dst = ei + e;

    char* ws = (char*)d_ws;
    size_t o = 0;
    int* deg = (int*)(ws + o);          o += ((size_t)n * 4 + 511) & ~(size_t)511;
    float* dinv = (float*)(ws + o);     o += ((size_t)n * 4 + 511) & ~(size_t)511;
    float* bufA = (float*)(ws + o);     o += ((size_t)n * 64 * 4 + 511) & ~(size_t)511;
    float* bufB = (float*)(ws + o);     o += ((size_t)n * 64 * 4 + 511) & ~(size_t)511;

    const size_t rowbytes = (size_t)n * 64 * 4;

    // degrees & dinv
    hipLaunchKernelGGL(deg_init_kernel, dim3((n + 255) / 256), dim3(256), 0, stream, deg, n);
    hipLaunchKernelGGL(deg_count_kernel, dim3((e + 255) / 256), dim3(256), 0, stream, dst, deg, e);
    hipLaunchKernelGGL(dinv_kernel, dim3((n + 255) / 256), dim3(256), 0, stream, deg, dinv, n);

    // ----- GCN layer 1: h1 = relu(conv(x, W1, b1)) -----
    hipLaunchKernelGGL(matmul64_scale_kernel, dim3((n + 3) / 4), dim3(256), 0, stream, x, W1, dinv, bufA, n);
    hipMemcpyAsync(bufB, bufA, rowbytes, hipMemcpyDeviceToDevice, stream);    // acc init = self-loop term
    hipLaunchKernelGGL(aggregate_kernel, dim3(((size_t)e * 64 + 255) / 256), dim3(256), 0, stream, src, dst, bufA, bufB, e);
    hipLaunchKernelGGL(finalize_kernel, dim3((n * 64 + 255) / 256), dim3(256), 0, stream, bufB, dinv, b1, bufA, n, 1);
    // h1 in bufA

    // ----- GCN layer 2: gnn = conv(h1, W2, b2) -----
    hipLaunchKernelGGL(matmul64_scale_kernel, dim3((n + 3) / 4), dim3(256), 0, stream, bufA, W2, dinv, bufB, n);
    hipMemcpyAsync(bufA, bufB, rowbytes, hipMemcpyDeviceToDevice, stream);
    hipLaunchKernelGGL(aggregate_kernel, dim3(((size_t)e * 64 + 255) / 256), dim3(256), 0, stream, src, dst, bufB, bufA, e);
    hipLaunchKernelGGL(finalize_kernel, dim3((n * 64 + 255) / 256), dim3(256), 0, stream, bufA, dinv, b2, bufB, n, 0);
    // gnn_out in bufB

    // ----- MLP head -----
    hipLaunchKernelGGL(out_init_kernel, dim3((n * 3 + 255) / 256), dim3(256), 0, stream, bp2, out, n);
    int nb = (n + 63) / 64;
    hipLaunchKernelGGL(mlp_gemm_kernel, dim3(nb * 8), dim3(256), 0, stream, bufB, x, Wp1, bp1, Wp2, out, n);
}

// Round 3
// 532.529 us; speedup vs baseline: 2.5223x; 1.7925x over previous
//
#include <hip/hip_runtime.h>

__device__ __forceinline__ void atomic_add_f32(float* p, float v) {
    __hip_atomic_fetch_add(p, v, __ATOMIC_RELAXED, __HIP_MEMORY_SCOPE_AGENT);
}

__global__ void zero_int_kernel(int* __restrict__ p, int n) {
    int i = blockIdx.x * blockDim.x + threadIdx.x;
    if (i < n) p[i] = 0;
}

__global__ void count_kernel(const int* __restrict__ dst, int* __restrict__ counts, int e) {
    int i = blockIdx.x * blockDim.x + threadIdx.x;
    if (i < e) atomicAdd(&counts[dst[i]], 1);
}

// block-local exclusive scan over 1024 elems (256 thr x 4)
__global__ void scan1_kernel(const int* __restrict__ counts, int* __restrict__ offs,
                             int* __restrict__ bsum, int n) {
    __shared__ int lds[256];
    int tid = threadIdx.x;
    int base = blockIdx.x * 1024 + tid * 4;
    int v0 = 0, v1 = 0, v2 = 0, v3 = 0;
    if (base + 3 < n) {
        int4 q = *(const int4*)(counts + base);
        v0 = q.x; v1 = q.y; v2 = q.z; v3 = q.w;
    } else {
        if (base + 0 < n) v0 = counts[base + 0];
        if (base + 1 < n) v1 = counts[base + 1];
        if (base + 2 < n) v2 = counts[base + 2];
        if (base + 3 < n) v3 = counts[base + 3];
    }
    int s1 = v0 + v1, s2 = s1 + v2, s3 = s2 + v3;
    lds[tid] = s3;
    __syncthreads();
    for (int off = 1; off < 256; off <<= 1) {
        int t = (tid >= off) ? lds[tid - off] : 0;
        __syncthreads();
        lds[tid] += t;
        __syncthreads();
    }
    int excl = lds[tid] - s3;
    if (base + 0 < n) offs[base + 0] = excl;
    if (base + 1 < n) offs[base + 1] = excl + v0;
    if (base + 2 < n) offs[base + 2] = excl + s1;
    if (base + 3 < n) offs[base + 3] = excl + s2;
    if (tid == 255) bsum[blockIdx.x] = lds[255];
}

__global__ void scan2_kernel(int* __restrict__ bsum, int nb) {
    __shared__ int lds[128];
    int tid = threadIdx.x;
    int v = (tid < nb) ? bsum[tid] : 0;
    lds[tid] = v;
    __syncthreads();
    for (int off = 1; off < 128; off <<= 1) {
        int t = (tid >= off) ? lds[tid - off] : 0;
        __syncthreads();
        lds[tid] += t;
        __syncthreads();
    }
    if (tid < nb) bsum[tid] = lds[tid] - v;
}

__global__ void scan3_kernel(int* __restrict__ offs, int* __restrict__ cursor,
                             const int* __restrict__ bsum, const int* __restrict__ counts,
                             float* __restrict__ dinv, int n) {
    int i = blockIdx.x * blockDim.x + threadIdx.x;
    if (i >= n) return;
    int o = offs[i] + bsum[i >> 10];
    offs[i] = o;
    cursor[i] = o;
    dinv[i] = rsqrtf((float)(counts[i] + 1));   // +1 self-loop
}

__global__ void fill_kernel(const int* __restrict__ src, const int* __restrict__ dst,
                            int* __restrict__ cursor, int* __restrict__ csr, int e) {
    int i = blockIdx.x * blockDim.x + threadIdx.x;
    if (i >= e) return;
    int d = dst[i];
    int slot = atomicAdd(&cursor[d], 1);
    csr[slot] = src[i];
}

// out[node][c] = (sum_k in[node][k] * W[k][c]) * dinv[node]   (W is 64x64 row-major)
__global__ void matmul64_scale_kernel(const float* __restrict__ in, const float* __restrict__ W,
                                      const float* __restrict__ dinv, float* __restrict__ out, int n) {
    __shared__ __align__(16) float wlds[64 * 64];
    __shared__ __align__(16) float xlds[4][64];
    int tid = threadIdx.x;
    #pragma unroll
    for (int i = 0; i < 16; ++i) wlds[tid + i * 256] = W[tid + i * 256];
    int r = tid >> 6, c = tid & 63;
    int node = blockIdx.x * 4 + r;
    if (node < n) xlds[r][c] = in[node * 64 + c];
    __syncthreads();
    if (node >= n) return;
    float acc = 0.f;
    #pragma unroll
    for (int k = 0; k < 64; ++k) acc = fmaf(xlds[r][k], wlds[k * 64 + c], acc);
    out[node * 64 + c] = acc * dinv[node];
}

// one wave per node: acc[lane] = ts[node][lane] + sum_{in-edges} ts[src][lane]; fused finalize
__global__ void agg_csr_kernel(const int* __restrict__ csr, const int* __restrict__ offs,
                               const int* __restrict__ cursor, const float* __restrict__ ts,
                               const float* __restrict__ dinv, const float* __restrict__ bias,
                               float* __restrict__ out, int n, int do_relu) {
    int node = blockIdx.x * 4 + (threadIdx.x >> 6);
    int lane = threadIdx.x & 63;
    if (node >= n) return;
    int start = offs[node];
    int end = cursor[node];          // == offs[node] + indeg after fill
    float a0 = ts[(size_t)node * 64 + lane];   // self-loop term
    float a1 = 0.f, a2 = 0.f, a3 = 0.f;
    for (int j = start; j < end; j += 64) {
        int cnt = min(64, end - j);
        int idx = (lane < cnt) ? csr[j + lane] : 0;
        int l = 0;
        for (; l + 3 < cnt; l += 4) {
            int s0 = __shfl(idx, l);
            int s1 = __shfl(idx, l + 1);
            int s2 = __shfl(idx, l + 2);
            int s3 = __shfl(idx, l + 3);
            a0 += ts[(size_t)s0 * 64 + lane];
            a1 += ts[(size_t)s1 * 64 + lane];
            a2 += ts[(size_t)s2 * 64 + lane];
            a3 += ts[(size_t)s3 * 64 + lane];
        }
        for (; l < cnt; ++l) {
            int s = __shfl(idx, l);
            a0 += ts[(size_t)s * 64 + lane];
        }
    }
    float v = dinv[node] * ((a0 + a1) + (a2 + a3)) + bias[lane];
    if (do_relu) v = fmaxf(v, 0.f);
    out[(size_t)node * 64 + lane] = v;
}

__global__ void out_init_kernel(const float* __restrict__ bp2, float* __restrict__ out, int n) {
    int idx = blockIdx.x * blockDim.x + threadIdx.x;
    if (idx < n * 3) out[idx] = bp2[idx % 3];
}

// MLP head GEMM: block = 128 nodes x 128 cols, 256 threads, 8x8 thread tile, K chunks of 64
// (chunk0 = gnn cols, chunk1 = x cols). W in LDS uses split-pair layout so the
// 16-lane col read is stride-16B (2-way, conflict-free).
__launch_bounds__(256, 2)
__global__ void mlp_gemm2_kernel(const float* __restrict__ gnn, const float* __restrict__ x,
                                 const float* __restrict__ Wp1, const float* __restrict__ bp1,
                                 const float* __restrict__ Wp2, float* __restrict__ out, int n) {
    __shared__ __align__(16) float a_lds[64 * 128];   // [k][node] 32 KB
    __shared__ __align__(16) float w_lds[64 * 128];   // [k][half][txg][4] 32 KB
    __shared__ __align__(16) float w2lds[128 * 3];
    __shared__ __align__(16) float b1lds[128];
    int tid = threadIdx.x;
    int cb = blockIdx.x & 3;
    int nb0 = (blockIdx.x >> 2) * 128;

    if (tid < 128) b1lds[tid] = bp1[cb * 128 + tid];
    for (int i = tid; i < 384; i += 256) w2lds[i] = Wp2[cb * 384 + i];

    float acc[8][8];
    #pragma unroll
    for (int m = 0; m < 8; ++m)
        #pragma unroll
        for (int c = 0; c < 8; ++c) acc[m][c] = 0.f;

    int tx = tid & 15, ty = tid >> 4;

    for (int kc = 0; kc < 2; ++kc) {
        __syncthreads();
        const float* Asrc = kc ? x : gnn;
        {
            int node = tid & 127;
            int g = nb0 + node;
            const float4* r4 = (const float4*)(Asrc + (size_t)g * 64);
            int kq0 = tid >> 7;
            #pragma unroll
            for (int i = 0; i < 8; ++i) {
                int kq = kq0 + i * 2;       // 0..15
                float4 v = make_float4(0.f, 0.f, 0.f, 0.f);
                if (g < n) v = r4[kq];
                int k = kq * 4;
                a_lds[(k + 0) * 128 + node] = v.x;
                a_lds[(k + 1) * 128 + node] = v.y;
                a_lds[(k + 2) * 128 + node] = v.z;
                a_lds[(k + 3) * 128 + node] = v.w;
            }
        }
        {
            #pragma unroll
            for (int i = 0; i < 8; ++i) {
                int f4 = tid + i * 256;            // 0..2047
                int k = f4 >> 5, c4 = f4 & 31;
                float4 v = *(const float4*)(Wp1 + (size_t)(kc * 64 + k) * 512 + cb * 128 + c4 * 4);
                *(float4*)(w_lds + k * 128 + (c4 & 1) * 64 + (c4 >> 1) * 4) = v;
            }
        }
        __syncthreads();
        const float* ap = a_lds + ty * 8;
        const float* bp = w_lds + tx * 4;
        #pragma unroll 8
        for (int k = 0; k < 64; ++k) {
            float4 A0 = *(const float4*)(ap + k * 128);
            float4 A1 = *(const float4*)(ap + k * 128 + 4);
            float4 B0 = *(const float4*)(bp + k * 128);        // cols tx*8+0..3
            float4 B1 = *(const float4*)(bp + k * 128 + 64);   // cols tx*8+4..7
            float av[8] = {A0.x, A0.y, A0.z, A0.w, A1.x, A1.y, A1.z, A1.w};
            float bv[8] = {B0.x, B0.y, B0.z, B0.w, B1.x, B1.y, B1.z, B1.w};
            #pragma unroll
            for (int m = 0; m < 8; ++m)
                #pragma unroll
                for (int c = 0; c < 8; ++c)
                    acc[m][c] = fmaf(av[m], bv[c], acc[m][c]);
        }
    }

    // epilogue: bias+relu, @Wp2 partial, shfl-reduce over tx, atomic add
    float pr[8][3];
    #pragma unroll
    for (int m = 0; m < 8; ++m) { pr[m][0] = 0.f; pr[m][1] = 0.f; pr[m][2] = 0.f; }
    #pragma unroll
    for (int c = 0; c < 8; ++c) {
        int lc = tx * 8 + c;
        float b1v = b1lds[lc];
        float w20 = w2lds[lc * 3 + 0], w21 = w2lds[lc * 3 + 1], w22 = w2lds[lc * 3 + 2];
        #pragma unroll
        for (int m = 0; m < 8; ++m) {
            float h = fmaxf(acc[m][c] + b1v, 0.f);
            pr[m][0] = fmaf(h, w20, pr[m][0]);
            pr[m][1] = fmaf(h, w21, pr[m][1]);
            pr[m][2] = fmaf(h, w22, pr[m][2]);
        }
    }
    #pragma unroll
    for (int m = 0; m < 8; ++m)
        #pragma unroll
        for (int j = 0; j < 3; ++j) {
            float v = pr[m][j];
            v += __shfl_xor(v, 1);
            v += __shfl_xor(v, 2);
            v += __shfl_xor(v, 4);
            v += __shfl_xor(v, 8);
            pr[m][j] = v;
        }
    if (tx == 0) {
        #pragma unroll
        for (int m = 0; m < 8; ++m) {
            int node = nb0 + ty * 8 + m;
            if (node < n) {
                atomic_add_f32(&out[(size_t)node * 3 + 0], pr[m][0]);
                atomic_add_f32(&out[(size_t)node * 3 + 1], pr[m][1]);
                atomic_add_f32(&out[(size_t)node * 3 + 2], pr[m][2]);
            }
        }
    }
}

extern "C" void kernel_launch(void* const* d_in, const int* in_sizes, int n_in,
                              void* d_out, int out_size, void* d_ws, size_t ws_size,
                              hipStream_t stream) {
    const float* x   = (const float*)d_in[0];
    const int*   ei  = (const int*)d_in[1];   // [2][E]
    const float* W1  = (const float*)d_in[2];
    const float* b1  = (const float*)d_in[3];
    const float* W2  = (const float*)d_in[4];
    const float* b2  = (const float*)d_in[5];
    const float* Wp1 = (const float*)d_in[6];
    const float* bp1 = (const float*)d_in[7];
    const float* Wp2 = (const float*)d_in[8];
    const float* bp2 = (const float*)d_in[9];
    float* out = (float*)d_out;

    const int n = in_sizes[0] / 64;
    const int e = in_sizes[1] / 2;
    const int* src = ei;
    const int* dst = ei + e;

    char* ws = (char*)d_ws;
    size_t o = 0;
    int* counts = (int*)(ws + o);   o += ((size_t)n * 4 + 511) & ~(size_t)511;
    int* offs   = (int*)(ws + o);   o += ((size_t)n * 4 + 511) & ~(size_t)511;
    int* cursor = (int*)(ws + o);   o += ((size_t)n * 4 + 511) & ~(size_t)511;
    int* bsum   = (int*)(ws + o);   o += 512;
    float* dinv = (float*)(ws + o); o += ((size_t)n * 4 + 511) & ~(size_t)511;
    int* csr    = (int*)(ws + o);   o += ((size_t)e * 4 + 511) & ~(size_t)511;
    float* bufA = (float*)(ws + o); o += ((size_t)n * 64 * 4 + 511) & ~(size_t)511;
    float* bufB = (float*)(ws + o); o += ((size_t)n * 64 * 4 + 511) & ~(size_t)511;

    int nb1 = (n + 1023) / 1024;   // <= 128 for n <= 131072

    // CSR build + dinv
    hipLaunchKernelGGL(zero_int_kernel, dim3((n + 255) / 256), dim3(256), 0, stream, counts, n);
    hipLaunchKernelGGL(count_kernel, dim3((e + 255) / 256), dim3(256), 0, stream, dst, counts, e);
    hipLaunchKernelGGL(scan1_kernel, dim3(nb1), dim3(256), 0, stream, counts, offs, bsum, n);
    hipLaunchKernelGGL(scan2_kernel, dim3(1), dim3(128), 0, stream, bsum, nb1);
    hipLaunchKernelGGL(scan3_kernel, dim3((n + 255) / 256), dim3(256), 0, stream, offs, cursor, bsum, counts, dinv, n);
    hipLaunchKernelGGL(fill_kernel, dim3((e + 255) / 256), dim3(256), 0, stream, src, dst, cursor, csr, e);

    // ----- GCN layer 1: h1 = relu(conv(x, W1, b1)) -----
    hipLaunchKernelGGL(matmul64_scale_kernel, dim3((n + 3) / 4), dim3(256), 0, stream, x, W1, dinv, bufA, n);
    hipLaunchKernelGGL(agg_csr_kernel, dim3((n + 3) / 4), dim3(256), 0, stream, csr, offs, cursor, bufA, dinv, b1, bufB, n, 1);

    // ----- GCN layer 2: gnn = conv(h1, W2, b2) -----
    hipLaunchKernelGGL(matmul64_scale_kernel, dim3((n + 3) / 4), dim3(256), 0, stream, bufB, W2, dinv, bufA, n);
    hipLaunchKernelGGL(agg_csr_kernel, dim3((n + 3) / 4), dim3(256), 0, stream, csr, offs, cursor, bufA, dinv, b2, bufB, n, 0);

    // ----- MLP head -----
    hipLaunchKernelGGL(out_init_kernel, dim3((n * 3 + 255) / 256), dim3(256), 0, stream, bp2, out, n);
    int nnb = (n + 127) / 128;
    hipLaunchKernelGGL(mlp_gemm2_kernel, dim3(nnb * 4), dim3(256), 0, stream, bufB, x, Wp1, bp1, Wp2, out, n);
}

// Round 4
// 503.827 us; speedup vs baseline: 2.6660x; 1.0570x over previous
//
#include <hip/hip_runtime.h>

typedef unsigned short ushort_t;
typedef unsigned int uint_t;
typedef __attribute__((ext_vector_type(8))) short bf16x8;
typedef __attribute__((ext_vector_type(4))) float f32x4;

__device__ __forceinline__ void atomic_add_f32(float* p, float v) {
    __hip_atomic_fetch_add(p, v, __ATOMIC_RELAXED, __HIP_MEMORY_SCOPE_AGENT);
}

__device__ __forceinline__ unsigned short f2bf(float f) {
    unsigned int u = __float_as_uint(f);
    unsigned int r = (u + 0x7FFFu + ((u >> 16) & 1u)) >> 16;   // round-to-nearest-even
    return (unsigned short)r;
}
__device__ __forceinline__ float bf2f(unsigned short h) {
    return __uint_as_float((unsigned int)h << 16);
}

__global__ void zero_int_kernel(int* __restrict__ p, int n) {
    int i = blockIdx.x * blockDim.x + threadIdx.x;
    if (i < n) p[i] = 0;
}

__global__ void count_kernel(const int* __restrict__ dst, int* __restrict__ counts, int e) {
    int i = blockIdx.x * blockDim.x + threadIdx.x;
    if (i < e) atomicAdd(&counts[dst[i]], 1);
}

// block-local exclusive scan over 1024 elems (256 thr x 4)
__global__ void scan1_kernel(const int* __restrict__ counts, int* __restrict__ offs,
                             int* __restrict__ bsum, int n) {
    __shared__ int lds[256];
    int tid = threadIdx.x;
    int base = blockIdx.x * 1024 + tid * 4;
    int v0 = 0, v1 = 0, v2 = 0, v3 = 0;
    if (base + 3 < n) {
        int4 q = *(const int4*)(counts + base);
        v0 = q.x; v1 = q.y; v2 = q.z; v3 = q.w;
    } else {
        if (base + 0 < n) v0 = counts[base + 0];
        if (base + 1 < n) v1 = counts[base + 1];
        if (base + 2 < n) v2 = counts[base + 2];
        if (base + 3 < n) v3 = counts[base + 3];
    }
    int s1 = v0 + v1, s2 = s1 + v2, s3 = s2 + v3;
    lds[tid] = s3;
    __syncthreads();
    for (int off = 1; off < 256; off <<= 1) {
        int t = (tid >= off) ? lds[tid - off] : 0;
        __syncthreads();
        lds[tid] += t;
        __syncthreads();
    }
    int excl = lds[tid] - s3;
    if (base + 0 < n) offs[base + 0] = excl;
    if (base + 1 < n) offs[base + 1] = excl + v0;
    if (base + 2 < n) offs[base + 2] = excl + s1;
    if (base + 3 < n) offs[base + 3] = excl + s2;
    if (tid == 255) bsum[blockIdx.x] = lds[255];
}

__global__ void scan2_kernel(int* __restrict__ bsum, int nb) {
    __shared__ int lds[128];
    int tid = threadIdx.x;
    int v = (tid < nb) ? bsum[tid] : 0;
    lds[tid] = v;
    __syncthreads();
    for (int off = 1; off < 128; off <<= 1) {
        int t = (tid >= off) ? lds[tid - off] : 0;
        __syncthreads();
        lds[tid] += t;
        __syncthreads();
    }
    if (tid < nb) bsum[tid] = lds[tid] - v;
}

__global__ void scan3_kernel(int* __restrict__ offs, int* __restrict__ cursor,
                             const int* __restrict__ bsum, const int* __restrict__ counts,
                             float* __restrict__ dinv, int n) {
    int i = blockIdx.x * blockDim.x + threadIdx.x;
    if (i >= n) return;
    int o = offs[i] + bsum[i >> 10];
    offs[i] = o;
    cursor[i] = o;
    dinv[i] = rsqrtf((float)(counts[i] + 1));   // +1 self-loop
}

__global__ void fill_kernel(const int* __restrict__ src, const int* __restrict__ dst,
                            int* __restrict__ cursor, int* __restrict__ csr, int e) {
    int i = blockIdx.x * blockDim.x + threadIdx.x;
    if (i >= e) return;
    int d = dst[i];
    int slot = atomicAdd(&cursor[d], 1);
    csr[slot] = src[i];
}

// out[node][c] = (sum_k in[node][k] * W[k][c]) * dinv[node]   (W is 64x64 row-major)
__global__ void matmul64_scale_kernel(const float* __restrict__ in, const float* __restrict__ W,
                                      const float* __restrict__ dinv, float* __restrict__ out, int n) {
    __shared__ __align__(16) float wlds[64 * 64];
    __shared__ __align__(16) float xlds[4][64];
    int tid = threadIdx.x;
    #pragma unroll
    for (int i = 0; i < 16; ++i) wlds[tid + i * 256] = W[tid + i * 256];
    int r = tid >> 6, c = tid & 63;
    int node = blockIdx.x * 4 + r;
    if (node < n) xlds[r][c] = in[node * 64 + c];
    __syncthreads();
    if (node >= n) return;
    float acc = 0.f;
    #pragma unroll
    for (int k = 0; k < 64; ++k) acc = fmaf(xlds[r][k], wlds[k * 64 + c], acc);
    out[node * 64 + c] = acc * dinv[node];
}

// one wave per node, f32 out (layer 1, with relu)
__global__ void agg_csr_kernel(const int* __restrict__ csr, const int* __restrict__ offs,
                               const int* __restrict__ cursor, const float* __restrict__ ts,
                               const float* __restrict__ dinv, const float* __restrict__ bias,
                               float* __restrict__ out, int n) {
    int node = blockIdx.x * 4 + (threadIdx.x >> 6);
    int lane = threadIdx.x & 63;
    if (node >= n) return;
    int start = offs[node];
    int end = cursor[node];
    float a0 = ts[(size_t)node * 64 + lane];
    float a1 = 0.f, a2 = 0.f, a3 = 0.f;
    for (int j = start; j < end; j += 64) {
        int cnt = min(64, end - j);
        int idx = (lane < cnt) ? csr[j + lane] : 0;
        int l = 0;
        for (; l + 3 < cnt; l += 4) {
            int s0 = __shfl(idx, l);
            int s1 = __shfl(idx, l + 1);
            int s2 = __shfl(idx, l + 2);
            int s3 = __shfl(idx, l + 3);
            a0 += ts[(size_t)s0 * 64 + lane];
            a1 += ts[(size_t)s1 * 64 + lane];
            a2 += ts[(size_t)s2 * 64 + lane];
            a3 += ts[(size_t)s3 * 64 + lane];
        }
        for (; l < cnt; ++l) {
            int s = __shfl(idx, l);
            a0 += ts[(size_t)s * 64 + lane];
        }
    }
    float v = dinv[node] * ((a0 + a1) + (a2 + a3)) + bias[lane];
    out[(size_t)node * 64 + lane] = fmaxf(v, 0.f);
}

// layer 2: same gather, epilogue writes split-bf16 hi/lo in MFMA fragment order (A cols 0..63)
__global__ void agg_csr_bf16_kernel(const int* __restrict__ csr, const int* __restrict__ offs,
                                    const int* __restrict__ cursor, const float* __restrict__ ts,
                                    const float* __restrict__ dinv, const float* __restrict__ bias,
                                    unsigned short* __restrict__ Ahi, unsigned short* __restrict__ Alo, int n) {
    int node = blockIdx.x * 4 + (threadIdx.x >> 6);
    int lane = threadIdx.x & 63;
    if (node >= n) return;
    int start = offs[node];
    int end = cursor[node];
    float a0 = ts[(size_t)node * 64 + lane];
    float a1 = 0.f, a2 = 0.f, a3 = 0.f;
    for (int j = start; j < end; j += 64) {
        int cnt = min(64, end - j);
        int idx = (lane < cnt) ? csr[j + lane] : 0;
        int l = 0;
        for (; l + 3 < cnt; l += 4) {
            int s0 = __shfl(idx, l);
            int s1 = __shfl(idx, l + 1);
            int s2 = __shfl(idx, l + 2);
            int s3 = __shfl(idx, l + 3);
            a0 += ts[(size_t)s0 * 64 + lane];
            a1 += ts[(size_t)s1 * 64 + lane];
            a2 += ts[(size_t)s2 * 64 + lane];
            a3 += ts[(size_t)s3 * 64 + lane];
        }
        for (; l < cnt; ++l) {
            int s = __shfl(idx, l);
            a0 += ts[(size_t)s * 64 + lane];
        }
    }
    float v = dinv[node] * ((a0 + a1) + (a2 + a3)) + bias[lane];
    unsigned short h = f2bf(v);
    unsigned short lo = f2bf(v - bf2f(h));
    // fragment-order address: k = lane (0..63), region (nt = node>>4, s = k>>5)
    int nt = node >> 4, r15 = node & 15;
    int s = lane >> 5, l4 = (lane >> 3) & 3, i = lane & 7;
    size_t a = (((size_t)nt * 4 + s) * 64 + l4 * 16 + r15) * 8 + i;
    Ahi[a] = h; Alo[a] = lo;
}

// x -> A cols 64..127, split-bf16, fragment order
__global__ void xcvt_kernel(const float* __restrict__ x, unsigned short* __restrict__ Ahi,
                            unsigned short* __restrict__ Alo, int n) {
    int idx = blockIdx.x * 256 + threadIdx.x;
    if (idx >= n * 64) return;
    int node = idx >> 6, k = idx & 63;
    float v = x[idx];
    unsigned short h = f2bf(v);
    unsigned short lo = f2bf(v - bf2f(h));
    int gk = 64 + k;
    int nt = node >> 4, r15 = node & 15;
    int s = gk >> 5, l4 = (gk >> 3) & 3, i = gk & 7;
    size_t a = (((size_t)nt * 4 + s) * 64 + l4 * 16 + r15) * 8 + i;
    Ahi[a] = h; Alo[a] = lo;
}

// Wp1 [128][512] row-major -> fragment-order split-bf16 W^T regions (t = col-tile 0..31, s = 0..3)
__global__ void wcvt_kernel(const float* __restrict__ Wp1, unsigned short* __restrict__ Whi,
                            unsigned short* __restrict__ Wlo) {
    int reg = blockIdx.x;              // 0..127 = t*4 + s
    int t = reg >> 2, s = reg & 3;
    int lane = threadIdx.x;            // 64
    int col = t * 16 + (lane & 15);
    int k0 = s * 32 + (lane >> 4) * 8;
    unsigned short hv[8], lv[8];
    #pragma unroll
    for (int i = 0; i < 8; ++i) {
        float v = Wp1[(size_t)(k0 + i) * 512 + col];
        hv[i] = f2bf(v);
        lv[i] = f2bf(v - bf2f(hv[i]));
    }
    size_t base = ((size_t)reg * 64 + lane) * 8;
    #pragma unroll
    for (int i = 0; i < 8; ++i) { Whi[base + i] = hv[i]; Wlo[base + i] = lv[i]; }
}

__global__ void out_init_kernel(const float* __restrict__ bp2, float* __restrict__ out, int n) {
    int idx = blockIdx.x * blockDim.x + threadIdx.x;
    if (idx < n * 3) out[idx] = bp2[idx % 3];
}

__device__ __forceinline__ void load_step(const unsigned short* __restrict__ Ahi,
                                          const unsigned short* __restrict__ Alo,
                                          const unsigned short* __restrict__ Whi,
                                          const unsigned short* __restrict__ Wlo,
                                          const size_t aoff[4], const size_t boff[4], int s,
                                          bf16x8 (&ah)[4], bf16x8 (&al)[4],
                                          bf16x8 (&bh)[4], bf16x8 (&bl)[4]) {
    size_t so = (size_t)s * 512;   // 64 lanes * 8 ushorts per region step
    #pragma unroll
    for (int q = 0; q < 4; ++q) {
        ah[q] = *(const bf16x8*)(Ahi + aoff[q] + so);
        al[q] = *(const bf16x8*)(Alo + aoff[q] + so);
        bh[q] = *(const bf16x8*)(Whi + boff[q] + so);
        bl[q] = *(const bf16x8*)(Wlo + boff[q] + so);
    }
}

__device__ __forceinline__ void mfma_step(const bf16x8 (&ah)[4], const bf16x8 (&al)[4],
                                          const bf16x8 (&bh)[4], const bf16x8 (&bl)[4],
                                          f32x4 (&acc)[4][4]) {
    #pragma unroll
    for (int rt = 0; rt < 4; ++rt)
        #pragma unroll
        for (int ct = 0; ct < 4; ++ct) {
            acc[rt][ct] = __builtin_amdgcn_mfma_f32_16x16x32_bf16(ah[rt], bh[ct], acc[rt][ct], 0, 0, 0);
            acc[rt][ct] = __builtin_amdgcn_mfma_f32_16x16x32_bf16(ah[rt], bl[ct], acc[rt][ct], 0, 0, 0);
            acc[rt][ct] = __builtin_amdgcn_mfma_f32_16x16x32_bf16(al[rt], bh[ct], acc[rt][ct], 0, 0, 0);
        }
}

// MLP head: block = 128 nodes x 128 cols (4 waves, each 64x64 via 16 MFMA tiles), K=128 in 4 steps.
// All operands loaded fragment-direct from global (no LDS). Split-bf16 3-term product.
__launch_bounds__(256, 2)
__global__ void mlp_mfma_kernel(const unsigned short* __restrict__ Ahi, const unsigned short* __restrict__ Alo,
                                const unsigned short* __restrict__ Whi, const unsigned short* __restrict__ Wlo,
                                const float* __restrict__ bp1, const float* __restrict__ Wp2,
                                float* __restrict__ out, int n) {
    int tid = threadIdx.x;
    int wave = tid >> 6, lane = tid & 63;
    int l15 = lane & 15, l4 = lane >> 4;
    int cb = blockIdx.x & 3;
    int node0 = (blockIdx.x >> 2) * 128;
    int wr = wave >> 1, wc = wave & 1;
    int nt0 = (node0 >> 4) + wr * 4;      // node-tile base
    int t0 = cb * 8 + wc * 4;             // col-tile base

    size_t aoff[4], boff[4];
    #pragma unroll
    for (int q = 0; q < 4; ++q) {
        aoff[q] = (((size_t)(nt0 + q) * 4) * 64 + lane) * 8;
        boff[q] = (((size_t)(t0 + q) * 4) * 64 + lane) * 8;
    }

    f32x4 acc[4][4];
    #pragma unroll
    for (int rt = 0; rt < 4; ++rt)
        #pragma unroll
        for (int ct = 0; ct < 4; ++ct) acc[rt][ct] = (f32x4){0.f, 0.f, 0.f, 0.f};

    bf16x8 eah[4], eal[4], ebh[4], ebl[4];
    bf16x8 oah[4], oal[4], obh[4], obl[4];

    load_step(Ahi, Alo, Whi, Wlo, aoff, boff, 0, eah, eal, ebh, ebl);
    load_step(Ahi, Alo, Whi, Wlo, aoff, boff, 1, oah, oal, obh, obl);
    mfma_step(eah, eal, ebh, ebl, acc);
    load_step(Ahi, Alo, Whi, Wlo, aoff, boff, 2, eah, eal, ebh, ebl);
    mfma_step(oah, oal, obh, obl, acc);
    load_step(Ahi, Alo, Whi, Wlo, aoff, boff, 3, oah, oal, obh, obl);
    mfma_step(eah, eal, ebh, ebl, acc);
    mfma_step(oah, oal, obh, obl, acc);

    // epilogue: bias + relu + @Wp2, reduce over 16-lane col group, atomics
    float b1v[4], w20[4], w21[4], w22[4];
    #pragma unroll
    for (int ct = 0; ct < 4; ++ct) {
        int c = (t0 + ct) * 16 + l15;
        b1v[ct] = bp1[c];
        w20[ct] = Wp2[c * 3 + 0];
        w21[ct] = Wp2[c * 3 + 1];
        w22[ct] = Wp2[c * 3 + 2];
    }
    #pragma unroll
    for (int rt = 0; rt < 4; ++rt) {
        #pragma unroll
        for (int r = 0; r < 4; ++r) {
            float p0 = 0.f, p1 = 0.f, p2 = 0.f;
            #pragma unroll
            for (int ct = 0; ct < 4; ++ct) {
                float h = fmaxf(acc[rt][ct][r] + b1v[ct], 0.f);
                p0 = fmaf(h, w20[ct], p0);
                p1 = fmaf(h, w21[ct], p1);
                p2 = fmaf(h, w22[ct], p2);
            }
            p0 += __shfl_xor(p0, 1); p0 += __shfl_xor(p0, 2); p0 += __shfl_xor(p0, 4); p0 += __shfl_xor(p0, 8);
            p1 += __shfl_xor(p1, 1); p1 += __shfl_xor(p1, 2); p1 += __shfl_xor(p1, 4); p1 += __shfl_xor(p1, 8);
            p2 += __shfl_xor(p2, 1); p2 += __shfl_xor(p2, 2); p2 += __shfl_xor(p2, 4); p2 += __shfl_xor(p2, 8);
            if (l15 == 0) {
                int node = node0 + wr * 64 + rt * 16 + l4 * 4 + r;
                if (node < n) {
                    atomic_add_f32(&out[(size_t)node * 3 + 0], p0);
                    atomic_add_f32(&out[(size_t)node * 3 + 1], p1);
                    atomic_add_f32(&out[(size_t)node * 3 + 2], p2);
                }
            }
        }
    }
}

extern "C" void kernel_launch(void* const* d_in, const int* in_sizes, int n_in,
                              void* d_out, int out_size, void* d_ws, size_t ws_size,
                              hipStream_t stream) {
    const float* x   = (const float*)d_in[0];
    const int*   ei  = (const int*)d_in[1];   // [2][E]
    const float* W1  = (const float*)d_in[2];
    const float* b1  = (const float*)d_in[3];
    const float* W2  = (const float*)d_in[4];
    const float* b2  = (const float*)d_in[5];
    const float* Wp1 = (const float*)d_in[6];
    const float* bp1 = (const float*)d_in[7];
    const float* Wp2 = (const float*)d_in[8];
    const float* bp2 = (const float*)d_in[9];
    float* out = (float*)d_out;

    const int n = in_sizes[0] / 64;
    const int e = in_sizes[1] / 2;
    const int pad_n = (n + 127) & ~127;
    const int* src = ei;
    const int* dst = ei + e;

    char* ws = (char*)d_ws;
    size_t o = 0;
    int* counts = (int*)(ws + o);            o += ((size_t)n * 4 + 511) & ~(size_t)511;
    int* offs   = (int*)(ws + o);            o += ((size_t)n * 4 + 511) & ~(size_t)511;
    int* cursor = (int*)(ws + o);            o += ((size_t)n * 4 + 511) & ~(size_t)511;
    int* bsum   = (int*)(ws + o);            o += 512;
    float* dinv = (float*)(ws + o);          o += ((size_t)n * 4 + 511) & ~(size_t)511;
    int* csr    = (int*)(ws + o);            o += ((size_t)e * 4 + 511) & ~(size_t)511;
    float* bufA = (float*)(ws + o);          o += ((size_t)pad_n * 64 * 4 + 511) & ~(size_t)511;
    // Ahi overlays bufB (h1): h1 is dead once matmul2 has consumed it
    char* regB  = ws + o;                    o += ((size_t)pad_n * 128 * 2 + 511) & ~(size_t)511;
    float* bufB = (float*)regB;
    unsigned short* Ahi = (unsigned short*)regB;
    unsigned short* Alo = (unsigned short*)(ws + o); o += ((size_t)pad_n * 128 * 2 + 511) & ~(size_t)511;
    unsigned short* Whi = (unsigned short*)(ws + o); o += 512 * 128 * 2;
    unsigned short* Wlo = (unsigned short*)(ws + o); o += 512 * 128 * 2;

    int nb1 = (n + 1023) / 1024;

    // CSR build + dinv
    hipLaunchKernelGGL(zero_int_kernel, dim3((n + 255) / 256), dim3(256), 0, stream, counts, n);
    hipLaunchKernelGGL(count_kernel, dim3((e + 255) / 256), dim3(256), 0, stream, dst, counts, e);
    hipLaunchKernelGGL(scan1_kernel, dim3(nb1), dim3(256), 0, stream, counts, offs, bsum, n);
    hipLaunchKernelGGL(scan2_kernel, dim3(1), dim3(128), 0, stream, bsum, nb1);
    hipLaunchKernelGGL(scan3_kernel, dim3((n + 255) / 256), dim3(256), 0, stream, offs, cursor, bsum, counts, dinv, n);
    hipLaunchKernelGGL(fill_kernel, dim3((e + 255) / 256), dim3(256), 0, stream, src, dst, cursor, csr, e);

    // Wp1 decompose (independent)
    hipLaunchKernelGGL(wcvt_kernel, dim3(128), dim3(64), 0, stream, Wp1, Whi, Wlo);

    // ----- GCN layer 1: h1 = relu(conv(x, W1, b1)) -----
    hipLaunchKernelGGL(matmul64_scale_kernel, dim3((n + 3) / 4), dim3(256), 0, stream, x, W1, dinv, bufA, n);
    hipLaunchKernelGGL(agg_csr_kernel, dim3((n + 3) / 4), dim3(256), 0, stream, csr, offs, cursor, bufA, dinv, b1, bufB, n);

    // ----- GCN layer 2: ts2 = (h1 @ W2) * dinv -----
    hipLaunchKernelGGL(matmul64_scale_kernel, dim3((n + 3) / 4), dim3(256), 0, stream, bufB, W2, dinv, bufA, n);
    // h1 (bufB) now dead -> region becomes Ahi
    hipLaunchKernelGGL(xcvt_kernel, dim3((n * 64 + 255) / 256), dim3(256), 0, stream, x, Ahi, Alo, n);
    hipLaunchKernelGGL(agg_csr_bf16_kernel, dim3((n + 3) / 4), dim3(256), 0, stream, csr, offs, cursor, bufA, dinv, b2, Ahi, Alo, n);

    // ----- MLP head (split-bf16 MFMA) -----
    hipLaunchKernelGGL(out_init_kernel, dim3((n * 3 + 255) / 256), dim3(256), 0, stream, bp2, out, n);
    int nblk = pad_n / 128;
    hipLaunchKernelGGL(mlp_mfma_kernel, dim3(nblk * 4), dim3(256), 0, stream, Ahi, Alo, Whi, Wlo, bp1, Wp2, out, n);
}

// Round 5
// 396.158 us; speedup vs baseline: 3.3905x; 1.2718x over previous
//
#include <hip/hip_runtime.h>

typedef unsigned short u16;
typedef __attribute__((ext_vector_type(8))) short bf16x8;
typedef __attribute__((ext_vector_type(4))) float f32x4;

__device__ __forceinline__ void atomic_add_f32(float* p, float v) {
    __hip_atomic_fetch_add(p, v, __ATOMIC_RELAXED, __HIP_MEMORY_SCOPE_AGENT);
}

__device__ __forceinline__ unsigned short f2bf(float f) {
    unsigned int u = __float_as_uint(f);
    unsigned int r = (u + 0x7FFFu + ((u >> 16) & 1u)) >> 16;   // round-to-nearest-even
    return (unsigned short)r;
}
__device__ __forceinline__ float bf2f(unsigned short h) {
    return __uint_as_float((unsigned int)h << 16);
}

__global__ void zero_int_kernel(int* __restrict__ p, int n) {
    int i = blockIdx.x * blockDim.x + threadIdx.x;
    if (i < n) p[i] = 0;
}

__global__ void count_kernel(const int* __restrict__ dst, int* __restrict__ counts, int e) {
    int i = blockIdx.x * blockDim.x + threadIdx.x;
    if (i < e) atomicAdd(&counts[dst[i]], 1);
}

// block-local exclusive scan over 1024 elems (256 thr x 4)
__global__ void scan1_kernel(const int* __restrict__ counts, int* __restrict__ offs,
                             int* __restrict__ bsum, int n) {
    __shared__ int lds[256];
    int tid = threadIdx.x;
    int base = blockIdx.x * 1024 + tid * 4;
    int v0 = 0, v1 = 0, v2 = 0, v3 = 0;
    if (base + 3 < n) {
        int4 q = *(const int4*)(counts + base);
        v0 = q.x; v1 = q.y; v2 = q.z; v3 = q.w;
    } else {
        if (base + 0 < n) v0 = counts[base + 0];
        if (base + 1 < n) v1 = counts[base + 1];
        if (base + 2 < n) v2 = counts[base + 2];
        if (base + 3 < n) v3 = counts[base + 3];
    }
    int s1 = v0 + v1, s2 = s1 + v2, s3 = s2 + v3;
    lds[tid] = s3;
    __syncthreads();
    for (int off = 1; off < 256; off <<= 1) {
        int t = (tid >= off) ? lds[tid - off] : 0;
        __syncthreads();
        lds[tid] += t;
        __syncthreads();
    }
    int excl = lds[tid] - s3;
    if (base + 0 < n) offs[base + 0] = excl;
    if (base + 1 < n) offs[base + 1] = excl + v0;
    if (base + 2 < n) offs[base + 2] = excl + s1;
    if (base + 3 < n) offs[base + 3] = excl + s2;
    if (tid == 255) bsum[blockIdx.x] = lds[255];
}

__global__ void scan2_kernel(int* __restrict__ bsum, int nb) {
    __shared__ int lds[128];
    int tid = threadIdx.x;
    int v = (tid < nb) ? bsum[tid] : 0;
    lds[tid] = v;
    __syncthreads();
    for (int off = 1; off < 128; off <<= 1) {
        int t = (tid >= off) ? lds[tid - off] : 0;
        __syncthreads();
        lds[tid] += t;
        __syncthreads();
    }
    if (tid < nb) bsum[tid] = lds[tid] - v;
}

__global__ void scan3_kernel(int* __restrict__ offs, int* __restrict__ cursor,
                             const int* __restrict__ bsum, const int* __restrict__ counts,
                             float* __restrict__ dinv, int n) {
    int i = blockIdx.x * blockDim.x + threadIdx.x;
    if (i >= n) return;
    int o = offs[i] + bsum[i >> 10];
    offs[i] = o;
    cursor[i] = o;
    dinv[i] = rsqrtf((float)(counts[i] + 1));   // +1 self-loop
}

__global__ void fill_kernel(const int* __restrict__ src, const int* __restrict__ dst,
                            int* __restrict__ cursor, int* __restrict__ csr, int e) {
    int i = blockIdx.x * blockDim.x + threadIdx.x;
    if (i >= e) return;
    int d = dst[i];
    int slot = atomicAdd(&cursor[d], 1);
    csr[slot] = src[i];
}

// out[node][c] = (sum_k in[node][k] * W[k][c]) * dinv[node]   (W is 64x64 row-major)
__global__ void matmul64_scale_kernel(const float* __restrict__ in, const float* __restrict__ W,
                                      const float* __restrict__ dinv, float* __restrict__ out, int n) {
    __shared__ __align__(16) float wlds[64 * 64];
    __shared__ __align__(16) float xlds[4][64];
    int tid = threadIdx.x;
    #pragma unroll
    for (int i = 0; i < 16; ++i) wlds[tid + i * 256] = W[tid + i * 256];
    int r = tid >> 6, c = tid & 63;
    int node = blockIdx.x * 4 + r;
    if (node < n) xlds[r][c] = in[node * 64 + c];
    __syncthreads();
    if (node >= n) return;
    float acc = 0.f;
    #pragma unroll
    for (int k = 0; k < 64; ++k) acc = fmaf(xlds[r][k], wlds[k * 64 + c], acc);
    out[node * 64 + c] = acc * dinv[node];
}

// one wave per node, f32 out (layer 1, with relu), 8-deep gather pipeline
__global__ void agg_csr_kernel(const int* __restrict__ csr, const int* __restrict__ offs,
                               const int* __restrict__ cursor, const float* __restrict__ ts,
                               const float* __restrict__ dinv, const float* __restrict__ bias,
                               float* __restrict__ out, int n) {
    int node = blockIdx.x * 4 + (threadIdx.x >> 6);
    int lane = threadIdx.x & 63;
    if (node >= n) return;
    int start = offs[node];
    int end = cursor[node];
    float a0 = ts[(size_t)node * 64 + lane];
    float a1 = 0.f, a2 = 0.f, a3 = 0.f;
    for (int j = start; j < end; j += 64) {
        int cnt = min(64, end - j);
        int idx = (lane < cnt) ? csr[j + lane] : 0;
        int l = 0;
        for (; l + 7 < cnt; l += 8) {
            int s0 = __shfl(idx, l);
            int s1 = __shfl(idx, l + 1);
            int s2 = __shfl(idx, l + 2);
            int s3 = __shfl(idx, l + 3);
            int s4 = __shfl(idx, l + 4);
            int s5 = __shfl(idx, l + 5);
            int s6 = __shfl(idx, l + 6);
            int s7 = __shfl(idx, l + 7);
            float v0 = ts[(size_t)s0 * 64 + lane];
            float v1 = ts[(size_t)s1 * 64 + lane];
            float v2 = ts[(size_t)s2 * 64 + lane];
            float v3 = ts[(size_t)s3 * 64 + lane];
            float v4 = ts[(size_t)s4 * 64 + lane];
            float v5 = ts[(size_t)s5 * 64 + lane];
            float v6 = ts[(size_t)s6 * 64 + lane];
            float v7 = ts[(size_t)s7 * 64 + lane];
            a0 += v0 + v4; a1 += v1 + v5; a2 += v2 + v6; a3 += v3 + v7;
        }
        for (; l + 3 < cnt; l += 4) {
            int s0 = __shfl(idx, l);
            int s1 = __shfl(idx, l + 1);
            int s2 = __shfl(idx, l + 2);
            int s3 = __shfl(idx, l + 3);
            a0 += ts[(size_t)s0 * 64 + lane];
            a1 += ts[(size_t)s1 * 64 + lane];
            a2 += ts[(size_t)s2 * 64 + lane];
            a3 += ts[(size_t)s3 * 64 + lane];
        }
        for (; l < cnt; ++l) {
            int s = __shfl(idx, l);
            a0 += ts[(size_t)s * 64 + lane];
        }
    }
    float v = dinv[node] * ((a0 + a1) + (a2 + a3)) + bias[lane];
    out[(size_t)node * 64 + lane] = fmaxf(v, 0.f);
}

// layer 2: same gather, epilogue writes split-bf16 hi/lo in MFMA fragment order (A cols 0..63)
__global__ void agg_csr_bf16_kernel(const int* __restrict__ csr, const int* __restrict__ offs,
                                    const int* __restrict__ cursor, const float* __restrict__ ts,
                                    const float* __restrict__ dinv, const float* __restrict__ bias,
                                    u16* __restrict__ Ahi, u16* __restrict__ Alo, int n) {
    int node = blockIdx.x * 4 + (threadIdx.x >> 6);
    int lane = threadIdx.x & 63;
    if (node >= n) return;
    int start = offs[node];
    int end = cursor[node];
    float a0 = ts[(size_t)node * 64 + lane];
    float a1 = 0.f, a2 = 0.f, a3 = 0.f;
    for (int j = start; j < end; j += 64) {
        int cnt = min(64, end - j);
        int idx = (lane < cnt) ? csr[j + lane] : 0;
        int l = 0;
        for (; l + 7 < cnt; l += 8) {
            int s0 = __shfl(idx, l);
            int s1 = __shfl(idx, l + 1);
            int s2 = __shfl(idx, l + 2);
            int s3 = __shfl(idx, l + 3);
            int s4 = __shfl(idx, l + 4);
            int s5 = __shfl(idx, l + 5);
            int s6 = __shfl(idx, l + 6);
            int s7 = __shfl(idx, l + 7);
            float v0 = ts[(size_t)s0 * 64 + lane];
            float v1 = ts[(size_t)s1 * 64 + lane];
            float v2 = ts[(size_t)s2 * 64 + lane];
            float v3 = ts[(size_t)s3 * 64 + lane];
            float v4 = ts[(size_t)s4 * 64 + lane];
            float v5 = ts[(size_t)s5 * 64 + lane];
            float v6 = ts[(size_t)s6 * 64 + lane];
            float v7 = ts[(size_t)s7 * 64 + lane];
            a0 += v0 + v4; a1 += v1 + v5; a2 += v2 + v6; a3 += v3 + v7;
        }
        for (; l + 3 < cnt; l += 4) {
            int s0 = __shfl(idx, l);
            int s1 = __shfl(idx, l + 1);
            int s2 = __shfl(idx, l + 2);
            int s3 = __shfl(idx, l + 3);
            a0 += ts[(size_t)s0 * 64 + lane];
            a1 += ts[(size_t)s1 * 64 + lane];
            a2 += ts[(size_t)s2 * 64 + lane];
            a3 += ts[(size_t)s3 * 64 + lane];
        }
        for (; l < cnt; ++l) {
            int s = __shfl(idx, l);
            a0 += ts[(size_t)s * 64 + lane];
        }
    }
    float v = dinv[node] * ((a0 + a1) + (a2 + a3)) + bias[lane];
    unsigned short h = f2bf(v);
    unsigned short lo = f2bf(v - bf2f(h));
    int nt = node >> 4, r15 = node & 15;
    int s = lane >> 5, l4 = (lane >> 3) & 3, i = lane & 7;
    size_t a = (((size_t)nt * 4 + s) * 64 + l4 * 16 + r15) * 8 + i;
    Ahi[a] = h; Alo[a] = lo;
}

// x -> A cols 64..127, split-bf16, fragment order
__global__ void xcvt_kernel(const float* __restrict__ x, u16* __restrict__ Ahi,
                            u16* __restrict__ Alo, int n) {
    int idx = blockIdx.x * 256 + threadIdx.x;
    if (idx >= n * 64) return;
    int node = idx >> 6, k = idx & 63;
    float v = x[idx];
    unsigned short h = f2bf(v);
    unsigned short lo = f2bf(v - bf2f(h));
    int gk = 64 + k;
    int nt = node >> 4, r15 = node & 15;
    int s = gk >> 5, l4 = (gk >> 3) & 3, i = gk & 7;
    size_t a = (((size_t)nt * 4 + s) * 64 + l4 * 16 + r15) * 8 + i;
    Ahi[a] = h; Alo[a] = lo;
}

// Wp1 [128][512] row-major -> fragment-order split-bf16 W^T regions (t = col-tile 0..31, s = 0..3)
__global__ void wcvt_kernel(const float* __restrict__ Wp1, u16* __restrict__ Whi,
                            u16* __restrict__ Wlo) {
    int reg = blockIdx.x;              // 0..127 = t*4 + s
    int t = reg >> 2, s = reg & 3;
    int lane = threadIdx.x;            // 64
    int col = t * 16 + (lane & 15);
    int k0 = s * 32 + (lane >> 4) * 8;
    unsigned short hv[8], lv[8];
    #pragma unroll
    for (int i = 0; i < 8; ++i) {
        float v = Wp1[(size_t)(k0 + i) * 512 + col];
        hv[i] = f2bf(v);
        lv[i] = f2bf(v - bf2f(hv[i]));
    }
    size_t base = ((size_t)reg * 64 + lane) * 8;
    #pragma unroll
    for (int i = 0; i < 8; ++i) { Whi[base + i] = hv[i]; Wlo[base + i] = lv[i]; }
}

__device__ __forceinline__ void loadW(const u16* __restrict__ Whi, const u16* __restrict__ Wlo,
                                      int t0, int s, int lane, bf16x8 (&bh)[4], bf16x8 (&bl)[4]) {
    #pragma unroll
    for (int ct = 0; ct < 4; ++ct) {
        size_t off = (((size_t)(t0 + ct) * 4 + s) * 64 + lane) * 8;
        bh[ct] = *(const bf16x8*)(Whi + off);
        bl[ct] = *(const bf16x8*)(Wlo + off);
    }
}

// MLP head, A-resident: wave = 32 nodes x ALL 512 cols; A frags loaded once,
// W streamed (double-buffered regs, L2-resident); per-lane pr accumulated across
// col-groups; single shfl-reduce + direct store (incl. bp2) at the end.
__launch_bounds__(256, 2)
__global__ void mlp_mfma2_kernel(const u16* __restrict__ Ahi, const u16* __restrict__ Alo,
                                 const u16* __restrict__ Whi, const u16* __restrict__ Wlo,
                                 const float* __restrict__ bp1, const float* __restrict__ Wp2,
                                 const float* __restrict__ bp2, float* __restrict__ out, int n) {
    __shared__ __align__(16) float b1lds[512];
    __shared__ __align__(16) float w2lds[512 * 3];
    int tid = threadIdx.x;
    b1lds[tid] = bp1[tid];
    b1lds[tid + 256] = bp1[tid + 256];
    #pragma unroll
    for (int i = 0; i < 6; ++i) w2lds[tid + i * 256] = Wp2[tid + i * 256];
    __syncthreads();

    int wave = tid >> 6, lane = tid & 63;
    int l15 = lane & 15, l4 = lane >> 4;
    int node0 = blockIdx.x * 128 + wave * 32;
    int nt0 = node0 >> 4;

    // A fragments: 2 regions x 4 k-steps x {hi,lo}
    bf16x8 ah[2][4], al[2][4];
    #pragma unroll
    for (int q = 0; q < 2; ++q)
        #pragma unroll
        for (int s = 0; s < 4; ++s) {
            size_t off = (((size_t)(nt0 + q) * 4 + s) * 64 + lane) * 8;
            ah[q][s] = *(const bf16x8*)(Ahi + off);
            al[q][s] = *(const bf16x8*)(Alo + off);
        }

    float pr[2][4][3];
    #pragma unroll
    for (int rt = 0; rt < 2; ++rt)
        #pragma unroll
        for (int r = 0; r < 4; ++r) { pr[rt][r][0] = 0.f; pr[rt][r][1] = 0.f; pr[rt][r][2] = 0.f; }

    bf16x8 bhE[4], blE[4], bhO[4], blO[4];
    loadW(Whi, Wlo, 0, 0, lane, bhE, blE);

#define MFMA_S(S, BH, BL)                                                                 \
    do {                                                                                  \
        _Pragma("unroll")                                                                 \
        for (int rt = 0; rt < 2; ++rt) {                                                  \
            _Pragma("unroll")                                                             \
            for (int ct = 0; ct < 4; ++ct) {                                              \
                acc[rt][ct] = __builtin_amdgcn_mfma_f32_16x16x32_bf16(ah[rt][S], BH[ct], acc[rt][ct], 0, 0, 0); \
                acc[rt][ct] = __builtin_amdgcn_mfma_f32_16x16x32_bf16(ah[rt][S], BL[ct], acc[rt][ct], 0, 0, 0); \
                acc[rt][ct] = __builtin_amdgcn_mfma_f32_16x16x32_bf16(al[rt][S], BH[ct], acc[rt][ct], 0, 0, 0); \
            }                                                                             \
        }                                                                                 \
    } while (0)

    for (int cg = 0; cg < 8; ++cg) {
        f32x4 acc[2][4];
        #pragma unroll
        for (int rt = 0; rt < 2; ++rt)
            #pragma unroll
            for (int ct = 0; ct < 4; ++ct) acc[rt][ct] = (f32x4){0.f, 0.f, 0.f, 0.f};

        int t0 = cg * 4;
        loadW(Whi, Wlo, t0, 1, lane, bhO, blO);
        MFMA_S(0, bhE, blE);
        loadW(Whi, Wlo, t0, 2, lane, bhE, blE);
        MFMA_S(1, bhO, blO);
        loadW(Whi, Wlo, t0, 3, lane, bhO, blO);
        MFMA_S(2, bhE, blE);
        loadW(Whi, Wlo, ((cg + 1) & 7) * 4, 0, lane, bhE, blE);   // wraps to cg=0, harmless
        MFMA_S(3, bhO, blO);

        // fold this col-group into per-lane partials
        #pragma unroll
        for (int ct = 0; ct < 4; ++ct) {
            int c = (t0 + ct) * 16 + l15;
            float b1v = b1lds[c];
            float w20 = w2lds[c * 3 + 0], w21 = w2lds[c * 3 + 1], w22 = w2lds[c * 3 + 2];
            #pragma unroll
            for (int rt = 0; rt < 2; ++rt)
                #pragma unroll
                for (int r = 0; r < 4; ++r) {
                    float h = fmaxf(acc[rt][ct][r] + b1v, 0.f);
                    pr[rt][r][0] = fmaf(h, w20, pr[rt][r][0]);
                    pr[rt][r][1] = fmaf(h, w21, pr[rt][r][1]);
                    pr[rt][r][2] = fmaf(h, w22, pr[rt][r][2]);
                }
        }
    }
#undef MFMA_S

    float c0 = bp2[0], c1 = bp2[1], c2 = bp2[2];
    #pragma unroll
    for (int rt = 0; rt < 2; ++rt)
        #pragma unroll
        for (int r = 0; r < 4; ++r)
            #pragma unroll
            for (int j = 0; j < 3; ++j) {
                float v = pr[rt][r][j];
                v += __shfl_xor(v, 1);
                v += __shfl_xor(v, 2);
                v += __shfl_xor(v, 4);
                v += __shfl_xor(v, 8);
                pr[rt][r][j] = v;
            }
    if (l15 == 0) {
        #pragma unroll
        for (int rt = 0; rt < 2; ++rt)
            #pragma unroll
            for (int r = 0; r < 4; ++r) {
                int node = node0 + rt * 16 + l4 * 4 + r;
                if (node < n) {
                    out[(size_t)node * 3 + 0] = pr[rt][r][0] + c0;
                    out[(size_t)node * 3 + 1] = pr[rt][r][1] + c1;
                    out[(size_t)node * 3 + 2] = pr[rt][r][2] + c2;
                }
            }
    }
}

extern "C" void kernel_launch(void* const* d_in, const int* in_sizes, int n_in,
                              void* d_out, int out_size, void* d_ws, size_t ws_size,
                              hipStream_t stream) {
    const float* x   = (const float*)d_in[0];
    const int*   ei  = (const int*)d_in[1];   // [2][E]
    const float* W1  = (const float*)d_in[2];
    const float* b1  = (const float*)d_in[3];
    const float* W2  = (const float*)d_in[4];
    const float* b2  = (const float*)d_in[5];
    const float* Wp1 = (const float*)d_in[6];
    const float* bp1 = (const float*)d_in[7];
    const float* Wp2 = (const float*)d_in[8];
    const float* bp2 = (const float*)d_in[9];
    float* out = (float*)d_out;

    const int n = in_sizes[0] / 64;
    const int e = in_sizes[1] / 2;
    const int pad_n = (n + 127) & ~127;
    const int* src = ei;
    const int* dst = ei + e;

    char* ws = (char*)d_ws;
    size_t o = 0;
    int* counts = (int*)(ws + o);            o += ((size_t)n * 4 + 511) & ~(size_t)511;
    int* offs   = (int*)(ws + o);            o += ((size_t)n * 4 + 511) & ~(size_t)511;
    int* cursor = (int*)(ws + o);            o += ((size_t)n * 4 + 511) & ~(size_t)511;
    int* bsum   = (int*)(ws + o);            o += 512;
    float* dinv = (float*)(ws + o);          o += ((size_t)n * 4 + 511) & ~(size_t)511;
    int* csr    = (int*)(ws + o);            o += ((size_t)e * 4 + 511) & ~(size_t)511;
    float* bufA = (float*)(ws + o);          o += ((size_t)pad_n * 64 * 4 + 511) & ~(size_t)511;
    // Ahi overlays bufB (h1): h1 is dead once matmul2 has consumed it
    char* regB  = ws + o;                    o += ((size_t)pad_n * 128 * 2 + 511) & ~(size_t)511;
    float* bufB = (float*)regB;
    u16* Ahi = (u16*)regB;
    u16* Alo = (u16*)(ws + o); o += ((size_t)pad_n * 128 * 2 + 511) & ~(size_t)511;
    u16* Whi = (u16*)(ws + o); o += 512 * 128 * 2;
    u16* Wlo = (u16*)(ws + o); o += 512 * 128 * 2;

    int nb1 = (n + 1023) / 1024;

    // CSR build + dinv
    hipLaunchKernelGGL(zero_int_kernel, dim3((n + 255) / 256), dim3(256), 0, stream, counts, n);
    hipLaunchKernelGGL(count_kernel, dim3((e + 255) / 256), dim3(256), 0, stream, dst, counts, e);
    hipLaunchKernelGGL(scan1_kernel, dim3(nb1), dim3(256), 0, stream, counts, offs, bsum, n);
    hipLaunchKernelGGL(scan2_kernel, dim3(1), dim3(128), 0, stream, bsum, nb1);
    hipLaunchKernelGGL(scan3_kernel, dim3((n + 255) / 256), dim3(256), 0, stream, offs, cursor, bsum, counts, dinv, n);
    hipLaunchKernelGGL(fill_kernel, dim3((e + 255) / 256), dim3(256), 0, stream, src, dst, cursor, csr, e);

    // Wp1 decompose (independent)
    hipLaunchKernelGGL(wcvt_kernel, dim3(128), dim3(64), 0, stream, Wp1, Whi, Wlo);

    // ----- GCN layer 1: h1 = relu(conv(x, W1, b1)) -----
    hipLaunchKernelGGL(matmul64_scale_kernel, dim3((n + 3) / 4), dim3(256), 0, stream, x, W1, dinv, bufA, n);
    hipLaunchKernelGGL(agg_csr_kernel, dim3((n + 3) / 4), dim3(256), 0, stream, csr, offs, cursor, bufA, dinv, b1, bufB, n);

    // ----- GCN layer 2: ts2 = (h1 @ W2) * dinv -----
    hipLaunchKernelGGL(matmul64_scale_kernel, dim3((n + 3) / 4), dim3(256), 0, stream, bufB, W2, dinv, bufA, n);
    // h1 (bufB) now dead -> region becomes Ahi
    hipLaunchKernelGGL(xcvt_kernel, dim3((n * 64 + 255) / 256), dim3(256), 0, stream, x, Ahi, Alo, n);
    hipLaunchKernelGGL(agg_csr_bf16_kernel, dim3((n + 3) / 4), dim3(256), 0, stream, csr, offs, cursor, bufA, dinv, b2, Ahi, Alo, n);

    // ----- MLP head (A-resident split-bf16 MFMA) -----
    hipLaunchKernelGGL(mlp_mfma2_kernel, dim3(pad_n / 128), dim3(256), 0, stream,
                       Ahi, Alo, Whi, Wlo, bp1, Wp2, bp2, out, n);
}